// Round 11
// baseline (261.516 us; speedup 1.0000x reference)
//
#include <hip/hip_runtime.h>

#define N_NODES 100000
#define DIM 128

typedef __attribute__((ext_vector_type(8))) short bf16x8;
typedef __attribute__((ext_vector_type(4))) float f32x4;
typedef __attribute__((ext_vector_type(8))) unsigned short ushort8;

__device__ __forceinline__ unsigned short f2bf(float f) {
    union { float f; unsigned u; } v; v.f = f;
    unsigned u = v.u + 0x7FFFu + ((v.u >> 16) & 1u);
    return (unsigned short)(u >> 16);
}
__device__ __forceinline__ float bl(unsigned u) { return __uint_as_float(u << 16); }
__device__ __forceinline__ float bh(unsigned u) { return __uint_as_float(u & 0xFFFF0000u); }

__device__ __forceinline__ void gload_lds16(const void* g, void* l) {
    __builtin_amdgcn_global_load_lds((const __attribute__((address_space(1))) void*)g,
                                     (__attribute__((address_space(3))) void*)l, 16, 0, 0);
}

// packed accumulate of one u32 (2 bf16 cols) into a float2 pair.
// lane cols: acc.x += lo-bf16 (exact), acc.y += raw-u32-as-f32 (= hi-bf16 with
// <1-ulp mantissa-extension noise — bounded, negligible after 1/c scaling).
__device__ __forceinline__ void pk2(float2& acc, unsigned u) {
    float2 v;
    v.x = __uint_as_float(u << 16);
    v.y = __uint_as_float(u);
    asm("v_pk_add_f32 %0, %1, %2" : "=v"(acc) : "v"(v), "v"(acc));
}

struct facc { float2 lo, hi; };   // cols (4sl,4sl+1) / (4sl+2,4sl+3)
__device__ __forceinline__ void accp(facc& a, uint2 v) {
    pk2(a.lo, v.x);
    pk2(a.hi, v.y);
}
__device__ __forceinline__ void redp(facc& a) {
    a.lo.x += __shfl_xor(a.lo.x, 32); a.lo.y += __shfl_xor(a.lo.y, 32);
    a.hi.x += __shfl_xor(a.hi.x, 32); a.hi.y += __shfl_xor(a.hi.y, 32);
}
__device__ __forceinline__ uint2 packp(facc a, float inv) {
    uint2 r;
    r.x = (unsigned)f2bf(a.lo.x * inv) | ((unsigned)f2bf(a.lo.y * inv) << 16);
    r.y = (unsigned)f2bf(a.hi.x * inv) | ((unsigned)f2bf(a.hi.y * inv) << 16);
    return r;
}

// ---------------- fused prep: x->bf16 + degree counts + weight slices ----------
__global__ void prep_kernel(const float* __restrict__ x, unsigned short* __restrict__ xb,
                            int n8, const int* __restrict__ e1d,
                            const int* __restrict__ e2d, const int* __restrict__ e3d,
                            int ng1, int ng12, int ngall, int* __restrict__ counts,
                            const float* __restrict__ A1, const float* __restrict__ A2,
                            const float* __restrict__ A3, const float* __restrict__ Cw,
                            unsigned short* __restrict__ bts, int nxblocks) {
    if ((int)blockIdx.x < nxblocks) {
        int i = blockIdx.x * 256 + threadIdx.x;
        if (i < n8) {
            const float4* p = reinterpret_cast<const float4*>(x) + (size_t)i * 2;
            float4 a = p[0], b = p[1];
            ushort8 o;
            o[0] = f2bf(a.x); o[1] = f2bf(a.y); o[2] = f2bf(a.z); o[3] = f2bf(a.w);
            o[4] = f2bf(b.x); o[5] = f2bf(b.y); o[6] = f2bf(b.z); o[7] = f2bf(b.w);
            *reinterpret_cast<ushort8*>(xb + (size_t)i * 8) = o;
        }
        if (i < ng1) atomicAdd(&counts[e1d[i]], 1);
        else if (i < ng12) atomicAdd(&counts[N_NODES + e2d[(size_t)(i - ng1) * 2]], 1);
        else if (i < ngall) atomicAdd(&counts[2 * N_NODES + e3d[(size_t)(i - ng12) * 3]], 1);
    } else {
        int kg = (blockIdx.x - nxblocks) * 2 + (threadIdx.x >> 7);  // 0..895
        int c = threadIdx.x & 127;
        float v;
        int slice, kp;
        if (kg < 128)      { slice = 0; kp = kg; v = A1[(size_t)kg * 128 + c]; }
        else if (kg < 384) { int k = kg - 128; slice = 1 + (k >> 7); kp = k & 127; v = A2[(size_t)k * 128 + c]; }
        else if (kg < 768) { int k = kg - 384; slice = 3 + (k >> 7); kp = k & 127; v = A3[(size_t)k * 128 + c]; }
        else               { int k = kg - 768; slice = 6; kp = k; v = Cw[(size_t)c * 128 + k]; }
        bts[(size_t)slice * 16384 + c * 128 + kp] = f2bf(v);
    }
}

// ---------------- hierarchical scan ----------------
__global__ __launch_bounds__(256) void scan_p1(const int* __restrict__ counts,
                                               int* __restrict__ partials) {
    __shared__ int red[256];
    int type = blockIdx.y, blk = blockIdx.x, tid = threadIdx.x;
    int base = blk * 4096 + tid * 16;
    int s = 0;
#pragma unroll
    for (int j = 0; j < 16; ++j) {
        int i = base + j;
        s += (i < N_NODES) ? counts[(size_t)type * N_NODES + i] : 0;
    }
    red[tid] = s;
    __syncthreads();
    for (int off = 128; off > 0; off >>= 1) {
        if (tid < off) red[tid] += red[tid + off];
        __syncthreads();
    }
    if (tid == 0) partials[type * 32 + blk] = red[0];
}

__global__ __launch_bounds__(256) void scan_p3(const int* __restrict__ counts,
                                               const int* __restrict__ partials,
                                               int* __restrict__ cursor) {
    __shared__ int tsum[256];
    __shared__ int baseoff;
    int type = blockIdx.y, blk = blockIdx.x, tid = threadIdx.x;
    if (tid == 0) {
        int r = 0;
        for (int b = 0; b < blk; ++b) r += partials[type * 32 + b];
        baseoff = r;
    }
    int base = blk * 4096 + tid * 16;
    int v[16];
    int s = 0;
#pragma unroll
    for (int j = 0; j < 16; ++j) {
        int i = base + j;
        v[j] = (i < N_NODES) ? counts[(size_t)type * N_NODES + i] : 0;
        s += v[j];
    }
    tsum[tid] = s;
    __syncthreads();
    for (int off = 1; off < 256; off <<= 1) {
        int t2 = (tid >= off) ? tsum[tid - off] : 0;
        __syncthreads();
        tsum[tid] += t2;
        __syncthreads();
    }
    int run = tsum[tid] - s + baseoff;
#pragma unroll
    for (int j = 0; j < 16; ++j) {
        int i = base + j;
        if (i < N_NODES) cursor[(size_t)type * N_NODES + i] = run;
        run += v[j];
    }
}

// ---------------- counting-sort scatter: stores PRE-SCALED byte offsets --------
__global__ void scatter_all_kernel(const int* __restrict__ e1, const int* __restrict__ e2,
                                   const int* __restrict__ e3, int ne1, int ne2, int ne3,
                                   int ng1, int ng12, int ngall, int* __restrict__ cursor,
                                   int* __restrict__ s1, int2* __restrict__ s2,
                                   int4* __restrict__ s3) {
    int g = blockIdx.x * 256 + threadIdx.x;
    if (g < ng1) {
        int d = e1[ne1 + g];
        s1[atomicAdd(&cursor[d], 1)] = e1[g] << 8;
    } else if (g < ng12) {
        int k = g - ng1;
        int d = e2[ne2 + 2 * (size_t)k];
        int2 v; v.x = e2[2 * (size_t)k] << 8; v.y = e2[2 * (size_t)k + 1] << 8;
        s2[atomicAdd(&cursor[N_NODES + d], 1)] = v;
    } else if (g < ngall) {
        int k = g - ng12;
        int d = e3[ne3 + 3 * (size_t)k];
        int4 v; v.x = e3[3 * (size_t)k] << 8; v.y = e3[3 * (size_t)k + 1] << 8;
        v.z = e3[3 * (size_t)k + 2] << 8; v.w = 0;
        s3[atomicAdd(&cursor[2 * N_NODES + d], 1)] = v;
    }
}

// ---------------- dest-centric x-space aggregation (pk_add inner loop) ---------
__global__ __launch_bounds__(256) void aggregate_x_kernel(
    const unsigned short* __restrict__ xb,
    const int* __restrict__ s1, const int2* __restrict__ s2, const int4* __restrict__ s3,
    const int* __restrict__ counts, const int* __restrict__ ends,
    unsigned short* __restrict__ gbf)
{
    int d = blockIdx.x * 4 + (threadIdx.x >> 6);
    if (d >= N_NODES) return;
    const int l = threadIdx.x & 63, hw = l >> 5, sl = l & 31;
    const char* xp = (const char*)xb + sl * 8;
    facc a0 = {{0,0},{0,0}}, a1 = {{0,0},{0,0}}, a2 = {{0,0},{0,0}};
    facc a3 = {{0,0},{0,0}}, a4 = {{0,0},{0,0}}, a5 = {{0,0},{0,0}};

    const int c1 = counts[d], c2 = counts[N_NODES + d], c3 = counts[2 * N_NODES + d];
    const int E1 = ends[d], E2 = ends[N_NODES + d], E3 = ends[2 * N_NODES + d];

    {   // type 1
        int i = E1 - c1 + hw;
        for (; i + 2 < E1; i += 4) {
            int o0 = s1[i], o1 = s1[i + 2];
            uint2 v0 = *reinterpret_cast<const uint2*>(xp + o0);
            uint2 v1 = *reinterpret_cast<const uint2*>(xp + o1);
            accp(a0, v0); accp(a0, v1);
        }
        if (i < E1) accp(a0, *reinterpret_cast<const uint2*>(xp + s1[i]));
    }
    {   // type 2
        int i = E2 - c2 + hw;
        for (; i + 2 < E2; i += 4) {
            int2 p0 = s2[i], p1 = s2[i + 2];
            uint2 va0 = *reinterpret_cast<const uint2*>(xp + p0.x);
            uint2 vb0 = *reinterpret_cast<const uint2*>(xp + p0.y);
            uint2 va1 = *reinterpret_cast<const uint2*>(xp + p1.x);
            uint2 vb1 = *reinterpret_cast<const uint2*>(xp + p1.y);
            accp(a1, va0); accp(a2, vb0); accp(a1, va1); accp(a2, vb1);
        }
        if (i < E2) {
            int2 p = s2[i];
            accp(a1, *reinterpret_cast<const uint2*>(xp + p.x));
            accp(a2, *reinterpret_cast<const uint2*>(xp + p.y));
        }
    }
    {   // type 3
        int i = E3 - c3 + hw;
        for (; i + 2 < E3; i += 4) {
            int4 p0 = s3[i], p1 = s3[i + 2];
            uint2 va0 = *reinterpret_cast<const uint2*>(xp + p0.x);
            uint2 vb0 = *reinterpret_cast<const uint2*>(xp + p0.y);
            uint2 vc0 = *reinterpret_cast<const uint2*>(xp + p0.z);
            uint2 va1 = *reinterpret_cast<const uint2*>(xp + p1.x);
            uint2 vb1 = *reinterpret_cast<const uint2*>(xp + p1.y);
            uint2 vc1 = *reinterpret_cast<const uint2*>(xp + p1.z);
            accp(a3, va0); accp(a4, vb0); accp(a5, vc0);
            accp(a3, va1); accp(a4, vb1); accp(a5, vc1);
        }
        if (i < E3) {
            int4 p = s3[i];
            accp(a3, *reinterpret_cast<const uint2*>(xp + p.x));
            accp(a4, *reinterpret_cast<const uint2*>(xp + p.y));
            accp(a5, *reinterpret_cast<const uint2*>(xp + p.z));
        }
    }
    redp(a0); redp(a1); redp(a2); redp(a3); redp(a4); redp(a5);
    if (hw == 0) {
        const float i1 = c1 ? 1.f / (float)c1 : 0.f;
        const float i2 = c2 ? 1.f / (float)c2 : 0.f;
        const float i3 = c3 ? 1.f / (float)c3 : 0.f;
        *reinterpret_cast<uint2*>(gbf + ((size_t)0 * N_NODES + d) * 128 + sl * 4) = packp(a0, i1);
        *reinterpret_cast<uint2*>(gbf + ((size_t)1 * N_NODES + d) * 128 + sl * 4) = packp(a1, i2);
        *reinterpret_cast<uint2*>(gbf + ((size_t)2 * N_NODES + d) * 128 + sl * 4) = packp(a2, i2);
        *reinterpret_cast<uint2*>(gbf + ((size_t)3 * N_NODES + d) * 128 + sl * 4) = packp(a3, i3);
        *reinterpret_cast<uint2*>(gbf + ((size_t)4 * N_NODES + d) * 128 + sl * 4) = packp(a4, i3);
        *reinterpret_cast<uint2*>(gbf + ((size_t)5 * N_NODES + d) * 128 + sl * 4) = packp(a5, i3);
    }
}

// ---------------- dense output GEMM: out = G'@concat(A) + x@CwT + Cb ----------
__global__ __launch_bounds__(256, 2) void gemm_out_kernel(
    const unsigned short* __restrict__ xb, const unsigned short* __restrict__ gbf,
    const unsigned short* __restrict__ bts, const float* __restrict__ Cb,
    float* __restrict__ out, int nnodes)
{
    __shared__ __align__(16) char smem[65536];

    const int tid = threadIdx.x;
    const int w = tid >> 6, l = tid & 63;
    const int g0 = blockIdx.x * 128;
    const int lrow = l & 15, lk = l >> 4;
    const int wr = (w & 1) * 64, wc = (w >> 1) * 64;

    const int q = (((l & 7) ^ (l >> 3)) << 4);
    const int inner = q & 63;
    const int rpq = ((l >> 3) << 1) + (q >> 6);

    int aoff[4];
#pragma unroll
    for (int mi = 0; mi < 4; ++mi) {
        int r = wr + mi * 16 + lrow;
        int P = r >> 1;
        aoff[mi] = P * 128 + ((((r & 1) << 6) | (lk << 4)) ^ ((P & 7) << 4));
    }

    f32x4 acc[4][4];
#pragma unroll
    for (int mi = 0; mi < 4; ++mi)
#pragma unroll
        for (int ni = 0; ni < 4; ++ni) acc[mi][ni] = (f32x4){0.f, 0.f, 0.f, 0.f};

    auto STAGE = [&](int c, int buf) {
#pragma unroll
        for (int i = 0; i < 2; ++i) {
            int u = w * 2 + i;
            int r = u * 16 + rpq;
            int row = (g0 + r < nnodes) ? g0 + r : 0;
            const char* src = (c < 6)
                ? (const char*)gbf + ((size_t)c * N_NODES + row) * 256
                : (const char*)xb + (size_t)row * 256;
#pragma unroll
            for (int t2 = 0; t2 < 4; ++t2)
                gload_lds16(src + t2 * 64 + inner, smem + buf * 32768 + t2 * 8192 + u * 1024);
        }
    };

    auto LOADB = [&](int c, bf16x8 (&dst)[4][4]) {
#pragma unroll
        for (int ks = 0; ks < 4; ++ks)
#pragma unroll
            for (int ni = 0; ni < 4; ++ni)
                dst[ks][ni] = *reinterpret_cast<const bf16x8*>(
                    bts + (size_t)c * 16384 + (wc + ni * 16 + lrow) * 128 + ks * 32 + lk * 8);
    };

    bf16x8 bgA[4][4], bgB[4][4];
    STAGE(0, 0);
    LOADB(0, bgA);
    asm volatile("s_waitcnt vmcnt(16)" ::: "memory");
    __builtin_amdgcn_s_barrier();
    asm volatile("" ::: "memory");

    auto BODY = [&](int c, bf16x8 (&cur)[4][4], bf16x8 (&nxt)[4][4]) {
        if (c + 1 < 7) {
            STAGE(c + 1, (c + 1) & 1);   // 8 loads, issued first (oldest)
            LOADB(c + 1, nxt);           // 16 loads
        }
        const int bb = (c & 1) * 32768;
#pragma unroll
        for (int ks = 0; ks < 4; ++ks) {
            bf16x8 af[4];
#pragma unroll
            for (int mi = 0; mi < 4; ++mi)
                af[mi] = *reinterpret_cast<const bf16x8*>(smem + bb + ks * 8192 + aoff[mi]);
            __builtin_amdgcn_s_setprio(1);
#pragma unroll
            for (int mi = 0; mi < 4; ++mi)
#pragma unroll
                for (int ni = 0; ni < 4; ++ni)
                    acc[mi][ni] = __builtin_amdgcn_mfma_f32_16x16x32_bf16(
                        af[mi], cur[ks][ni], acc[mi][ni], 0, 0, 0);
            __builtin_amdgcn_s_setprio(0);
        }
        if (c + 1 < 7) {
            // drain exactly the 8 stage loads (oldest); keep 16 B-loads in flight
            asm volatile("s_waitcnt vmcnt(16)" ::: "memory");
            __builtin_amdgcn_s_barrier();
            asm volatile("" ::: "memory");
        }
    };

    BODY(0, bgA, bgB);
    BODY(1, bgB, bgA);
    BODY(2, bgA, bgB);
    BODY(3, bgB, bgA);
    BODY(4, bgA, bgB);
    BODY(5, bgB, bgA);
    BODY(6, bgA, bgB);

    float bv[4];
#pragma unroll
    for (int ni = 0; ni < 4; ++ni) bv[ni] = Cb[wc + ni * 16 + lrow];
#pragma unroll
    for (int mi = 0; mi < 4; ++mi)
#pragma unroll
        for (int reg = 0; reg < 4; ++reg) {
            int g = g0 + wr + mi * 16 + lk * 4 + reg;
            if (g < nnodes) {
#pragma unroll
                for (int ni = 0; ni < 4; ++ni)
                    out[(size_t)g * DIM + wc + ni * 16 + lrow] = acc[mi][ni][reg] + bv[ni];
            }
        }
}

extern "C" void kernel_launch(void* const* d_in, const int* in_sizes, int n_in,
                              void* d_out, int out_size, void* d_ws, size_t ws_size,
                              hipStream_t stream) {
    const float* x  = (const float*)d_in[0];
    const int*   e1 = (const int*)d_in[1];
    const int*   e2 = (const int*)d_in[2];
    const int*   e3 = (const int*)d_in[3];
    const float* A1 = (const float*)d_in[4];
    const float* A2 = (const float*)d_in[5];
    const float* A3 = (const float*)d_in[6];
    const float* Cw = (const float*)d_in[7];
    const float* Cb = (const float*)d_in[8];
    float* out = (float*)d_out;

    const int ne1 = in_sizes[1] / 2, ne2 = in_sizes[2] / 2, ne3 = in_sizes[3] / 2;
    const int ng1 = ne1, ng2 = ne2 / 2, ng3 = ne3 / 3;
    const int N = N_NODES;

    int*  counts  = (int*)d_ws;                     // 3N
    int*  cursor  = counts + 3 * N;                 // 3N
    int4* s3      = (int4*)(cursor + 3 * N);        // ng3 (16B aligned)
    int2* s2      = (int2*)(s3 + ng3);              // ng2
    int*  s1      = (int*)(s2 + ng2);               // ng1
    int*  partials = s1 + ng1;                      // 96 used, pad 128
    unsigned short* bts = (unsigned short*)(partials + 128);   // 7*16384
    unsigned short* xb  = bts + 7 * 16384;                     // N*128
    unsigned short* gbf = xb + (size_t)N * 128;                // 6*N*128

    const int ngall = ng1 + ng2 + ng3;
    const int ng12 = ng1 + ng2;
    const int n8 = N * DIM / 8;
    const int nxblocks = (n8 + 255) / 256;

    hipMemsetAsync(counts, 0, (size_t)3 * N * sizeof(int), stream);
    prep_kernel<<<nxblocks + 448, 256, 0, stream>>>(
        x, xb, n8, e1 + ne1, e2 + ne2, e3 + ne3, ng1, ng12, ngall, counts,
        A1, A2, A3, Cw, bts, nxblocks);
    scan_p1<<<dim3(25, 3), 256, 0, stream>>>(counts, partials);
    scan_p3<<<dim3(25, 3), 256, 0, stream>>>(counts, partials, cursor);
    scatter_all_kernel<<<(ngall + 255) / 256, 256, 0, stream>>>(
        e1, e2, e3, ne1, ne2, ne3, ng1, ng12, ngall, cursor, s1, s2, s3);
    aggregate_x_kernel<<<(N + 3) / 4, 256, 0, stream>>>(
        xb, s1, s2, s3, counts, cursor, gbf);
    gemm_out_kernel<<<(N + 127) / 128, 256, 0, stream>>>(xb, gbf, bts, Cb, out, N);
}

// Round 12
// 253.106 us; speedup vs baseline: 1.0332x; 1.0332x over previous
//
#include <hip/hip_runtime.h>

#define N_NODES 100000
#define DIM 128

typedef __attribute__((ext_vector_type(8))) short bf16x8;
typedef __attribute__((ext_vector_type(4))) float f32x4;
typedef __attribute__((ext_vector_type(8))) unsigned short ushort8;

__device__ __forceinline__ unsigned short f2bf(float f) {
    union { float f; unsigned u; } v; v.f = f;
    unsigned u = v.u + 0x7FFFu + ((v.u >> 16) & 1u);
    return (unsigned short)(u >> 16);
}
__device__ __forceinline__ float bl(unsigned u) { return __uint_as_float(u << 16); }
__device__ __forceinline__ float bh(unsigned u) { return __uint_as_float(u & 0xFFFF0000u); }

__device__ __forceinline__ void gload_lds16(const void* g, void* l) {
    __builtin_amdgcn_global_load_lds((const __attribute__((address_space(1))) void*)g,
                                     (__attribute__((address_space(3))) void*)l, 16, 0, 0);
}

__device__ __forceinline__ void acc2(float4& a, uint2 v) {
    a.x += bl(v.x); a.y += bh(v.x); a.z += bl(v.y); a.w += bh(v.y);
}
__device__ __forceinline__ void red4(float4& a) {
    a.x += __shfl_xor(a.x, 32); a.y += __shfl_xor(a.y, 32);
    a.z += __shfl_xor(a.z, 32); a.w += __shfl_xor(a.w, 32);
}
__device__ __forceinline__ uint2 pack4s(float4 a, float inv) {
    uint2 r;
    r.x = (unsigned)f2bf(a.x * inv) | ((unsigned)f2bf(a.y * inv) << 16);
    r.y = (unsigned)f2bf(a.z * inv) | ((unsigned)f2bf(a.w * inv) << 16);
    return r;
}

// ---------------- fused prep: x->bf16 + degree counts + weight slices ----------
__global__ void prep_kernel(const float* __restrict__ x, unsigned short* __restrict__ xb,
                            int n8, const int* __restrict__ e1d,
                            const int* __restrict__ e2d, const int* __restrict__ e3d,
                            int ng1, int ng12, int ngall, int* __restrict__ counts,
                            const float* __restrict__ A1, const float* __restrict__ A2,
                            const float* __restrict__ A3, const float* __restrict__ Cw,
                            unsigned short* __restrict__ bts, int nxblocks) {
    if ((int)blockIdx.x < nxblocks) {
        int i = blockIdx.x * 256 + threadIdx.x;
        if (i < n8) {
            const float4* p = reinterpret_cast<const float4*>(x) + (size_t)i * 2;
            float4 a = p[0], b = p[1];
            ushort8 o;
            o[0] = f2bf(a.x); o[1] = f2bf(a.y); o[2] = f2bf(a.z); o[3] = f2bf(a.w);
            o[4] = f2bf(b.x); o[5] = f2bf(b.y); o[6] = f2bf(b.z); o[7] = f2bf(b.w);
            *reinterpret_cast<ushort8*>(xb + (size_t)i * 8) = o;
        }
        if (i < ng1) atomicAdd(&counts[e1d[i]], 1);
        else if (i < ng12) atomicAdd(&counts[N_NODES + e2d[(size_t)(i - ng1) * 2]], 1);
        else if (i < ngall) atomicAdd(&counts[2 * N_NODES + e3d[(size_t)(i - ng12) * 3]], 1);
    } else {
        int kg = (blockIdx.x - nxblocks) * 2 + (threadIdx.x >> 7);  // 0..895
        int c = threadIdx.x & 127;
        float v;
        int slice, kp;
        if (kg < 128)      { slice = 0; kp = kg; v = A1[(size_t)kg * 128 + c]; }
        else if (kg < 384) { int k = kg - 128; slice = 1 + (k >> 7); kp = k & 127; v = A2[(size_t)k * 128 + c]; }
        else if (kg < 768) { int k = kg - 384; slice = 3 + (k >> 7); kp = k & 127; v = A3[(size_t)k * 128 + c]; }
        else               { int k = kg - 768; slice = 6; kp = k; v = Cw[(size_t)c * 128 + k]; }
        bts[(size_t)slice * 16384 + c * 128 + kp] = f2bf(v);
    }
}

// ---------------- hierarchical scan ----------------
__global__ __launch_bounds__(256) void scan_p1(const int* __restrict__ counts,
                                               int* __restrict__ partials) {
    __shared__ int red[256];
    int type = blockIdx.y, blk = blockIdx.x, tid = threadIdx.x;
    int base = blk * 4096 + tid * 16;
    int s = 0;
#pragma unroll
    for (int j = 0; j < 16; ++j) {
        int i = base + j;
        s += (i < N_NODES) ? counts[(size_t)type * N_NODES + i] : 0;
    }
    red[tid] = s;
    __syncthreads();
    for (int off = 128; off > 0; off >>= 1) {
        if (tid < off) red[tid] += red[tid + off];
        __syncthreads();
    }
    if (tid == 0) partials[type * 32 + blk] = red[0];
}

__global__ __launch_bounds__(256) void scan_p3(const int* __restrict__ counts,
                                               const int* __restrict__ partials,
                                               int* __restrict__ cursor) {
    __shared__ int tsum[256];
    __shared__ int baseoff;
    int type = blockIdx.y, blk = blockIdx.x, tid = threadIdx.x;
    if (tid == 0) {
        int r = 0;
        for (int b = 0; b < blk; ++b) r += partials[type * 32 + b];
        baseoff = r;
    }
    int base = blk * 4096 + tid * 16;
    int v[16];
    int s = 0;
#pragma unroll
    for (int j = 0; j < 16; ++j) {
        int i = base + j;
        v[j] = (i < N_NODES) ? counts[(size_t)type * N_NODES + i] : 0;
        s += v[j];
    }
    tsum[tid] = s;
    __syncthreads();
    for (int off = 1; off < 256; off <<= 1) {
        int t2 = (tid >= off) ? tsum[tid - off] : 0;
        __syncthreads();
        tsum[tid] += t2;
        __syncthreads();
    }
    int run = tsum[tid] - s + baseoff;
#pragma unroll
    for (int j = 0; j < 16; ++j) {
        int i = base + j;
        if (i < N_NODES) cursor[(size_t)type * N_NODES + i] = run;
        run += v[j];
    }
}

// ---------------- counting-sort scatter: stores PRE-SCALED byte offsets --------
__global__ void scatter_all_kernel(const int* __restrict__ e1, const int* __restrict__ e2,
                                   const int* __restrict__ e3, int ne1, int ne2, int ne3,
                                   int ng1, int ng12, int ngall, int* __restrict__ cursor,
                                   int* __restrict__ s1, int2* __restrict__ s2,
                                   int4* __restrict__ s3) {
    int g = blockIdx.x * 256 + threadIdx.x;
    if (g < ng1) {
        int d = e1[ne1 + g];
        s1[atomicAdd(&cursor[d], 1)] = e1[g] << 8;
    } else if (g < ng12) {
        int k = g - ng1;
        int d = e2[ne2 + 2 * (size_t)k];
        int2 v; v.x = e2[2 * (size_t)k] << 8; v.y = e2[2 * (size_t)k + 1] << 8;
        s2[atomicAdd(&cursor[N_NODES + d], 1)] = v;
    } else if (g < ngall) {
        int k = g - ng12;
        int d = e3[ne3 + 3 * (size_t)k];
        int4 v; v.x = e3[3 * (size_t)k] << 8; v.y = e3[3 * (size_t)k + 1] << 8;
        v.z = e3[3 * (size_t)k + 2] << 8; v.w = 0;
        s3[atomicAdd(&cursor[2 * N_NODES + d], 1)] = v;
    }
}

// ---------------- dest-centric x-space aggregation (r10 version; traffic-bound) -
__global__ __launch_bounds__(256) void aggregate_x_kernel(
    const unsigned short* __restrict__ xb,
    const int* __restrict__ s1, const int2* __restrict__ s2, const int4* __restrict__ s3,
    const int* __restrict__ counts, const int* __restrict__ ends,
    unsigned short* __restrict__ gbf)
{
    int d = blockIdx.x * 4 + (threadIdx.x >> 6);
    if (d >= N_NODES) return;
    const int l = threadIdx.x & 63, hw = l >> 5, sl = l & 31;
    const char* xp = (const char*)xb + sl * 8;
    float4 a0 = {0,0,0,0}, a1 = {0,0,0,0}, a2 = {0,0,0,0};
    float4 a3 = {0,0,0,0}, a4 = {0,0,0,0}, a5 = {0,0,0,0};

    const int c1 = counts[d], c2 = counts[N_NODES + d], c3 = counts[2 * N_NODES + d];
    const int E1 = ends[d], E2 = ends[N_NODES + d], E3 = ends[2 * N_NODES + d];

    {   // type 1
        int i = E1 - c1 + hw;
        for (; i + 2 < E1; i += 4) {
            int o0 = s1[i], o1 = s1[i + 2];
            uint2 v0 = *reinterpret_cast<const uint2*>(xp + o0);
            uint2 v1 = *reinterpret_cast<const uint2*>(xp + o1);
            acc2(a0, v0); acc2(a0, v1);
        }
        if (i < E1) acc2(a0, *reinterpret_cast<const uint2*>(xp + s1[i]));
    }
    {   // type 2
        int i = E2 - c2 + hw;
        for (; i + 2 < E2; i += 4) {
            int2 p0 = s2[i], p1 = s2[i + 2];
            uint2 va0 = *reinterpret_cast<const uint2*>(xp + p0.x);
            uint2 vb0 = *reinterpret_cast<const uint2*>(xp + p0.y);
            uint2 va1 = *reinterpret_cast<const uint2*>(xp + p1.x);
            uint2 vb1 = *reinterpret_cast<const uint2*>(xp + p1.y);
            acc2(a1, va0); acc2(a2, vb0); acc2(a1, va1); acc2(a2, vb1);
        }
        if (i < E2) {
            int2 p = s2[i];
            acc2(a1, *reinterpret_cast<const uint2*>(xp + p.x));
            acc2(a2, *reinterpret_cast<const uint2*>(xp + p.y));
        }
    }
    {   // type 3
        int i = E3 - c3 + hw;
        for (; i + 2 < E3; i += 4) {
            int4 p0 = s3[i], p1 = s3[i + 2];
            uint2 va0 = *reinterpret_cast<const uint2*>(xp + p0.x);
            uint2 vb0 = *reinterpret_cast<const uint2*>(xp + p0.y);
            uint2 vc0 = *reinterpret_cast<const uint2*>(xp + p0.z);
            uint2 va1 = *reinterpret_cast<const uint2*>(xp + p1.x);
            uint2 vb1 = *reinterpret_cast<const uint2*>(xp + p1.y);
            uint2 vc1 = *reinterpret_cast<const uint2*>(xp + p1.z);
            acc2(a3, va0); acc2(a4, vb0); acc2(a5, vc0);
            acc2(a3, va1); acc2(a4, vb1); acc2(a5, vc1);
        }
        if (i < E3) {
            int4 p = s3[i];
            acc2(a3, *reinterpret_cast<const uint2*>(xp + p.x));
            acc2(a4, *reinterpret_cast<const uint2*>(xp + p.y));
            acc2(a5, *reinterpret_cast<const uint2*>(xp + p.z));
        }
    }
    red4(a0); red4(a1); red4(a2); red4(a3); red4(a4); red4(a5);
    if (hw == 0) {
        const float i1 = c1 ? 1.f / (float)c1 : 0.f;
        const float i2 = c2 ? 1.f / (float)c2 : 0.f;
        const float i3 = c3 ? 1.f / (float)c3 : 0.f;
        *reinterpret_cast<uint2*>(gbf + ((size_t)0 * N_NODES + d) * 128 + sl * 4) = pack4s(a0, i1);
        *reinterpret_cast<uint2*>(gbf + ((size_t)1 * N_NODES + d) * 128 + sl * 4) = pack4s(a1, i2);
        *reinterpret_cast<uint2*>(gbf + ((size_t)2 * N_NODES + d) * 128 + sl * 4) = pack4s(a2, i2);
        *reinterpret_cast<uint2*>(gbf + ((size_t)3 * N_NODES + d) * 128 + sl * 4) = pack4s(a3, i3);
        *reinterpret_cast<uint2*>(gbf + ((size_t)4 * N_NODES + d) * 128 + sl * 4) = pack4s(a4, i3);
        *reinterpret_cast<uint2*>(gbf + ((size_t)5 * N_NODES + d) * 128 + sl * 4) = pack4s(a5, i3);
    }
}

// ---------------- dense output GEMM, 28 x 8KB sub-chunk pipeline ----------------
// K = 896 = 28 slices of 32. LDS ring: 4 x 8KB (32KB total -> 3 blocks/CU).
// S staged 3 ahead / drained 1 ahead; B triple-buffered in regs, issued 2 ahead.
// One counted vmcnt + barrier per slice (exact compile-time bookkeeping).
__global__ __launch_bounds__(256, 3) void gemm_out_kernel(
    const unsigned short* __restrict__ xb, const unsigned short* __restrict__ gbf,
    const unsigned short* __restrict__ bts, const float* __restrict__ Cb,
    float* __restrict__ out, int nnodes)
{
    __shared__ __align__(16) char smem[32768];

    const int tid = threadIdx.x;
    const int w = tid >> 6, l = tid & 63;
    const int g0 = blockIdx.x * 128;
    const int lrow = l & 15, lk = l >> 4;
    const int wr = (w & 1) * 64, wc = (w >> 1) * 64;

    const int q = (((l & 7) ^ (l >> 3)) << 4);
    const int inner = q & 63;
    const int rpq = ((l >> 3) << 1) + (q >> 6);

    int aoff[4];
#pragma unroll
    for (int mi = 0; mi < 4; ++mi) {
        int r = wr + mi * 16 + lrow;
        int P = r >> 1;
        aoff[mi] = P * 128 + ((((r & 1) << 6) | (lk << 4)) ^ ((P & 7) << 4));
    }

    // per-thread staging addresses (2 rows)
    const char* srow[2];
#pragma unroll
    for (int i = 0; i < 2; ++i) {
        int u = w * 2 + i;
        int r = u * 16 + rpq;
        int row = (g0 + r < nnodes) ? g0 + r : 0;
        srow[i] = (const char*)(size_t)row;  // store row id; resolved per slice
    }
    const int u0 = w * 2, r0 = u0 * 16 + rpq, r1 = (u0 + 1) * 16 + rpq;
    const int row0 = (g0 + r0 < nnodes) ? g0 + r0 : 0;
    const int row1 = (g0 + r1 < nnodes) ? g0 + r1 : 0;

    f32x4 acc[4][4];
#pragma unroll
    for (int mi = 0; mi < 4; ++mi)
#pragma unroll
        for (int ni = 0; ni < 4; ++ni) acc[mi][ni] = (f32x4){0.f, 0.f, 0.f, 0.f};

    auto STAGE = [&](int s) {   // s = sub-chunk index [0,28)
        const int c = s >> 2, ks = s & 3;
        const int buf = s & 3;
        const char* b0 = (c < 6) ? (const char*)gbf + ((size_t)c * N_NODES + row0) * 256
                                 : (const char*)xb + (size_t)row0 * 256;
        const char* b1 = (c < 6) ? (const char*)gbf + ((size_t)c * N_NODES + row1) * 256
                                 : (const char*)xb + (size_t)row1 * 256;
        gload_lds16(b0 + ks * 64 + inner, smem + buf * 8192 + u0 * 1024);
        gload_lds16(b1 + ks * 64 + inner, smem + buf * 8192 + (u0 + 1) * 1024);
    };

    auto LOADB = [&](int s, bf16x8 (&dst)[4]) {
        const int c = s >> 2, ks = s & 3;
#pragma unroll
        for (int ni = 0; ni < 4; ++ni)
            dst[ni] = *reinterpret_cast<const bf16x8*>(
                bts + (size_t)c * 16384 + (wc + ni * 16 + lrow) * 128 + ks * 32 + lk * 8);
    };

    bf16x8 bg[3][4];
    // prologue: stages 0..2, B 0..1 (stages oldest)
    STAGE(0); STAGE(1); STAGE(2);
    LOADB(0, bg[0]); LOADB(1, bg[1]);

    // keep(s): loads allowed to remain in flight at body-s wait point
#define KEEPV(S) (4 * ((27 - (S)) < 0 ? 0 : ((27 - (S)) < 2 ? (27 - (S)) : 2)) + \
                  2 * ((26 - (S)) < 0 ? 0 : ((26 - (S)) < 2 ? (26 - (S)) : 2)))

#define GBODY(S)                                                                   \
    {                                                                              \
        if ((S) + 3 < 28) STAGE((S) + 3);                                          \
        if ((S) + 2 < 28) LOADB((S) + 2, bg[((S) + 2) % 3]);                       \
        asm volatile("s_waitcnt vmcnt(%0)" ::"i"(KEEPV(S)) : "memory");            \
        __builtin_amdgcn_s_barrier();                                              \
        asm volatile("" ::: "memory");                                             \
        bf16x8 af[4];                                                              \
        _Pragma("unroll") for (int mi = 0; mi < 4; ++mi) af[mi] =                  \
            *reinterpret_cast<const bf16x8*>(smem + ((S) & 3) * 8192 + aoff[mi]);  \
        __builtin_amdgcn_s_setprio(1);                                             \
        _Pragma("unroll") for (int mi = 0; mi < 4; ++mi)                           \
            _Pragma("unroll") for (int ni = 0; ni < 4; ++ni) acc[mi][ni] =         \
                __builtin_amdgcn_mfma_f32_16x16x32_bf16(af[mi], bg[(S) % 3][ni],   \
                                                        acc[mi][ni], 0, 0, 0);     \
        __builtin_amdgcn_s_setprio(0);                                             \
        __builtin_amdgcn_s_barrier();                                              \
    }

    GBODY(0)  GBODY(1)  GBODY(2)  GBODY(3)  GBODY(4)  GBODY(5)  GBODY(6)
    GBODY(7)  GBODY(8)  GBODY(9)  GBODY(10) GBODY(11) GBODY(12) GBODY(13)
    GBODY(14) GBODY(15) GBODY(16) GBODY(17) GBODY(18) GBODY(19) GBODY(20)
    GBODY(21) GBODY(22) GBODY(23) GBODY(24) GBODY(25) GBODY(26) GBODY(27)
#undef GBODY
#undef KEEPV

    float bv[4];
#pragma unroll
    for (int ni = 0; ni < 4; ++ni) bv[ni] = Cb[wc + ni * 16 + lrow];
#pragma unroll
    for (int mi = 0; mi < 4; ++mi)
#pragma unroll
        for (int reg = 0; reg < 4; ++reg) {
            int g = g0 + wr + mi * 16 + lk * 4 + reg;
            if (g < nnodes) {
#pragma unroll
                for (int ni = 0; ni < 4; ++ni)
                    out[(size_t)g * DIM + wc + ni * 16 + lrow] = acc[mi][ni][reg] + bv[ni];
            }
        }
}

extern "C" void kernel_launch(void* const* d_in, const int* in_sizes, int n_in,
                              void* d_out, int out_size, void* d_ws, size_t ws_size,
                              hipStream_t stream) {
    const float* x  = (const float*)d_in[0];
    const int*   e1 = (const int*)d_in[1];
    const int*   e2 = (const int*)d_in[2];
    const int*   e3 = (const int*)d_in[3];
    const float* A1 = (const float*)d_in[4];
    const float* A2 = (const float*)d_in[5];
    const float* A3 = (const float*)d_in[6];
    const float* Cw = (const float*)d_in[7];
    const float* Cb = (const float*)d_in[8];
    float* out = (float*)d_out;

    const int ne1 = in_sizes[1] / 2, ne2 = in_sizes[2] / 2, ne3 = in_sizes[3] / 2;
    const int ng1 = ne1, ng2 = ne2 / 2, ng3 = ne3 / 3;
    const int N = N_NODES;

    int*  counts  = (int*)d_ws;                     // 3N
    int*  cursor  = counts + 3 * N;                 // 3N
    int4* s3      = (int4*)(cursor + 3 * N);        // ng3 (16B aligned)
    int2* s2      = (int2*)(s3 + ng3);              // ng2
    int*  s1      = (int*)(s2 + ng2);               // ng1
    int*  partials = s1 + ng1;                      // 96 used, pad 128
    unsigned short* bts = (unsigned short*)(partials + 128);   // 7*16384
    unsigned short* xb  = bts + 7 * 16384;                     // N*128
    unsigned short* gbf = xb + (size_t)N * 128;                // 6*N*128

    const int ngall = ng1 + ng2 + ng3;
    const int ng12 = ng1 + ng2;
    const int n8 = N * DIM / 8;
    const int nxblocks = (n8 + 255) / 256;

    hipMemsetAsync(counts, 0, (size_t)3 * N * sizeof(int), stream);
    prep_kernel<<<nxblocks + 448, 256, 0, stream>>>(
        x, xb, n8, e1 + ne1, e2 + ne2, e3 + ne3, ng1, ng12, ngall, counts,
        A1, A2, A3, Cw, bts, nxblocks);
    scan_p1<<<dim3(25, 3), 256, 0, stream>>>(counts, partials);
    scan_p3<<<dim3(25, 3), 256, 0, stream>>>(counts, partials, cursor);
    scatter_all_kernel<<<(ngall + 255) / 256, 256, 0, stream>>>(
        e1, e2, e3, ne1, ne2, ne3, ng1, ng12, ngall, cursor, s1, s2, s3);
    aggregate_x_kernel<<<(N + 3) / 4, 256, 0, stream>>>(
        xb, s1, s2, s3, counts, cursor, gbf);
    gemm_out_kernel<<<(N + 127) / 128, 256, 0, stream>>>(xb, gbf, bts, Cb, out, N);
}